// Round 5
// baseline (183.407 us; speedup 1.0000x reference)
//
#include <hip/hip_runtime.h>
#include <math.h>

#define NROWS 8192
#define KDIM  768            // bytes per i8 row
#define BM 256
#define BN 256
#define HB 64                // half-tile (k-step) bytes per row = one 16x16x64
#define KT2 (KDIM / HB)      // 12 k-steps per bc sweep
#define NBC 4                // bc tiles swept per block
#define NT_ALL (NBC * KT2)   // 48 staged half-tiles per block

typedef int i32x4 __attribute__((ext_vector_type(4)));  // i8 MFMA A/B frag (16 B) and C/D

// monotonic float<->uint encoding so atomicMax(uint) == float max
static __device__ __forceinline__ unsigned enc_f(float f) {
    unsigned x = __float_as_uint(f);
    return (x & 0x80000000u) ? ~x : (x | 0x80000000u);
}
static __device__ __forceinline__ float dec_f(unsigned u) {
    unsigned x = (u & 0x80000000u) ? (u ^ 0x80000000u) : ~u;
    return __uint_as_float(x);
}

// one wave per row: fp32 normalize (exact), then symmetric int8 quantization
// with per-row scale amax/127. blocks 0..31 also init the out buffer.
__global__ __launch_bounds__(256) void normalize_quant_k(
        const float* __restrict__ ex, const float* __restrict__ ey,
        signed char* __restrict__ q, float* __restrict__ scales,
        unsigned* __restrict__ out) {
    if (blockIdx.x < NROWS / 256)
        out[blockIdx.x * 256 + threadIdx.x] = enc_f(-INFINITY);
    const int wave = threadIdx.x >> 6, lane = threadIdx.x & 63;
    const int grow = blockIdx.x * 4 + wave;          // 0..16383
    const float* src = (grow < NROWS) ? ex : ey;
    const int row = grow & (NROWS - 1);
    const float4* xr = (const float4*)(src + (size_t)row * KDIM);  // 192 float4
    float4 v[3];
    #pragma unroll
    for (int g = 0; g < 3; ++g) v[g] = xr[lane + g * 64];
    float ss = 0.f, am = 0.f;
    #pragma unroll
    for (int g = 0; g < 3; ++g) {
        ss += v[g].x * v[g].x + v[g].y * v[g].y + v[g].z * v[g].z + v[g].w * v[g].w;
        am = fmaxf(am, fmaxf(fmaxf(fabsf(v[g].x), fabsf(v[g].y)),
                             fmaxf(fabsf(v[g].z), fabsf(v[g].w))));
    }
    #pragma unroll
    for (int off = 32; off > 0; off >>= 1) {
        ss += __shfl_xor(ss, off);
        am = fmaxf(am, __shfl_xor(am, off));
    }
    const float scale = 1.0f / fmaxf(sqrtf(ss), 1e-8f);
    am = fmaxf(am * scale, 1e-12f);        // amax of the NORMALIZED row
    if (lane == 0) scales[grow] = am * (1.0f / 127.0f);
    const float si = scale * (127.0f / am);            // raw -> int8 code
    int* dr = (int*)(q + (size_t)grow * KDIM);         // 192 packed ints / row
    #pragma unroll
    for (int g = 0; g < 3; ++g) {
        int qx = min(127, max(-127, __float2int_rn(v[g].x * si)));
        int qy = min(127, max(-127, __float2int_rn(v[g].y * si)));
        int qz = min(127, max(-127, __float2int_rn(v[g].z * si)));
        int qw = min(127, max(-127, __float2int_rn(v[g].w * si)));
        dr[lane + g * 64] = (qx & 0xff) | ((qy & 0xff) << 8) |
                            ((qz & 0xff) << 16) | ((qw & 0xff) << 24);
    }
}

// R3's verified 8-phase schedule (m201-style: 2 phases/k-step, 16 MFMA each,
// counted vmcnt(8) depth-3 half-tile pipeline, conflict-free row-pair swizzle,
// 0 bank conflicts) + R4's proven 2D XCD-aware block decode.
// R3 alone: 112 us, pinned by 102 MB FETCH (each XCD streamed all of A x4).
// R4 mapping alone on the drain-limited 128^2 kernel: FETCH 102->18.6 MB but
// MfmaUtil stuck 27% (barrier-drain ceiling). This combines the two:
// each XCD owns an 8-br x 4-bcg rectangle -> working set 8 A-tiles (1.57 MB)
// + 16 B-tiles (3.14 MB) = 4.7 MB ~= L2; 32 blocks/XCD all co-resident.
// Bijective decode: br = (xcd>>1)*8 + (idx&7), bcg = (xcd&1)*4 + (idx>>3).
__global__ __launch_bounds__(512, 2) void gemm_rowmax_i8_k(
        const signed char* __restrict__ A, const signed char* __restrict__ B,
        const float* __restrict__ sa, const float* __restrict__ sb,
        unsigned* __restrict__ out) {
    __shared__ __attribute__((aligned(128))) signed char As[4][BM * HB];  // 64 KB
    __shared__ __attribute__((aligned(128))) signed char Bs[4][BN * HB];  // 64 KB

    const int tid  = threadIdx.x;
    const int wave = tid >> 6, lane = tid & 63;
    // 2D XCD-aware decode (speed-only heuristic; correctness independent)
    const int xcd = blockIdx.x & 7;        // dispatch round-robins XCDs
    const int idx = blockIdx.x >> 3;       // 0..31 within XCD
    const int br  = (xcd >> 1) * 8 + (idx & 7);   // 0..31
    const int bcg = (xcd & 1) * 4 + (idx >> 3);   // 0..7

    // --- staging: per half-tile, wave w loads rows w*32..w*32+31 of A and B
    // (2 issues of 16 rows). Per-lane inverse-swizzle source mapping:
    //   u = (lane&7) ^ (lane>>3);  srow = (lane>>3)*2 + (u>>2);  chunk = u&3
    const int u_     = (lane & 7) ^ (lane >> 3);
    const int srow   = ((lane >> 3) << 1) + (u_ >> 2);   // 0..15
    const int gch    = (u_ & 3) * 16;                    // byte chunk in 64-B slice
    const signed char* aStage =
        A + (size_t)(br * BM + wave * 32 + srow) * KDIM + gch;
    const int ldsW = wave * 2048;                        // 16 stripes x 128 B

    // --- compute geometry: wave (wm,wn) owns 128x64; frags 8mi x 4ni of 16x16
    const int wm = (wave >> 2) * 128, wn = (wave & 3) * 64;
    const int quad = lane >> 4, mrow = lane & 15;
    const int slot = (((mrow & 1) << 2) | quad) ^ (mrow >> 1);
    const int aOff = ((wm >> 1) + (mrow >> 1)) * 128 + slot * 16;  // + mi*1024
    const int bOff = ((wn >> 1) + (mrow >> 1)) * 128 + slot * 16;  // + ni*1024

    #define GLOAD(gp, lp)                                                         \
        __builtin_amdgcn_global_load_lds(                                         \
            (const __attribute__((address_space(1))) void*)(gp),                  \
            (__attribute__((address_space(3))) void*)(lp), 16, 0, 0)

    #define STAGE_A(sidx) do {                                                    \
        const int sA_ = (sidx); const int ktA_ = sA_ % KT2;                       \
        const signed char* ag_ = aStage + ktA_ * HB;                              \
        signed char* la_ = &As[sA_ & 3][ldsW];                                    \
        GLOAD(ag_, la_);                                                          \
        GLOAD(ag_ + 16 * KDIM, la_ + 1024);                                       \
    } while (0)

    #define STAGE_B(sidx) do {                                                    \
        const int sB_ = (sidx);                                                   \
        const int biB_ = sB_ / KT2, ktB_ = sB_ % KT2;                             \
        const signed char* bg_ = B + (size_t)((bcg * NBC + biB_) * BN             \
                                 + wave * 32 + srow) * KDIM + gch + ktB_ * HB;    \
        signed char* lb_ = &Bs[sB_ & 3][ldsW];                                    \
        GLOAD(bg_, lb_);                                                          \
        GLOAD(bg_ + 16 * KDIM, lb_ + 1024);                                       \
    } while (0)

    // prologue: half-tiles 0,1,2 in flight (12 loads/wave, ht-ordered), then
    // secure half-tile 0 (vmcnt(8): 12 issued - 8 outstanding = A0,B0 landed)
    // and rendezvous so every wave's stage-0 writes are visible.
    STAGE_A(0); STAGE_B(0);
    STAGE_A(1); STAGE_B(1);
    STAGE_A(2); STAGE_B(2);
    asm volatile("s_waitcnt vmcnt(8)" ::: "memory");
    __builtin_amdgcn_s_barrier();
    int s = 3, t = 0;

    #pragma unroll 1
    for (int bi = 0; bi < NBC; ++bi) {
        i32x4 acc[8][4] = {};
        #pragma unroll 1
        for (int kt = 0; kt < KT2; ++kt, ++t) {
            const int cb = t & 3;
            const signed char* aP = &As[cb][aOff];
            const signed char* bP = &Bs[cb][bOff];

            // ---- phase 0: B frags + A frags mi0..3, MFMA mi0..3 ----
            i32x4 bf[4], af[4];
            #pragma unroll
            for (int ni = 0; ni < 4; ++ni)
                bf[ni] = *(const i32x4*)(bP + ni * 1024);
            #pragma unroll
            for (int mi = 0; mi < 4; ++mi)
                af[mi] = *(const i32x4*)(aP + mi * 1024);
            if (s < NT_ALL) STAGE_A(s);
            __builtin_amdgcn_s_barrier();
            asm volatile("s_waitcnt lgkmcnt(0)" ::: "memory");
            __builtin_amdgcn_sched_barrier(0);
            __builtin_amdgcn_s_setprio(1);
            #pragma unroll
            for (int mi = 0; mi < 4; ++mi)
                #pragma unroll
                for (int ni = 0; ni < 4; ++ni)
                    acc[mi][ni] = __builtin_amdgcn_mfma_i32_16x16x64_i8(
                        af[mi], bf[ni], acc[mi][ni], 0, 0, 0);
            __builtin_amdgcn_s_setprio(0);
            __builtin_amdgcn_s_barrier();

            // ---- phase 1: A frags mi4..7 (reuse bf), MFMA mi4..7 ----
            i32x4 ag[4];
            #pragma unroll
            for (int mi = 0; mi < 4; ++mi)
                ag[mi] = *(const i32x4*)(aP + 4096 + mi * 1024);
            if (s < NT_ALL) { STAGE_B(s); ++s; }
            // counted wait: secure half-tile t+1; keep t+2, t+3 in flight.
            if (t < NT_ALL - 3)       asm volatile("s_waitcnt vmcnt(8)" ::: "memory");
            else if (t == NT_ALL - 3) asm volatile("s_waitcnt vmcnt(4)" ::: "memory");
            else if (t == NT_ALL - 2) asm volatile("s_waitcnt vmcnt(0)" ::: "memory");
            __builtin_amdgcn_s_barrier();
            asm volatile("s_waitcnt lgkmcnt(0)" ::: "memory");
            __builtin_amdgcn_sched_barrier(0);
            __builtin_amdgcn_s_setprio(1);
            #pragma unroll
            for (int mi = 0; mi < 4; ++mi)
                #pragma unroll
                for (int ni = 0; ni < 4; ++ni)
                    acc[4 + mi][ni] = __builtin_amdgcn_mfma_i32_16x16x64_i8(
                        ag[mi], bf[ni], acc[4 + mi][ni], 0, 0, 0);
            __builtin_amdgcn_s_setprio(0);
            __builtin_amdgcn_s_barrier();
        }

        // epilogue: registers + global only (no LDS, no barrier needed).
        // C/D layout 16x16: col = mrow, row = quad*4 + reg (dtype-independent).
        const int bc = bcg * NBC + bi;
        float sbv[4];
        #pragma unroll
        for (int ni = 0; ni < 4; ++ni)
            sbv[ni] = sb[bc * BN + wn + ni * 16 + mrow];
        const int row0 = br * BM + wm + quad * 4;
        #pragma unroll
        for (int mi = 0; mi < 8; ++mi) {
            #pragma unroll
            for (int r = 0; r < 4; ++r) {
                float v = fmaxf(fmaxf((float)acc[mi][0][r] * sbv[0],
                                      (float)acc[mi][1][r] * sbv[1]),
                                fmaxf((float)acc[mi][2][r] * sbv[2],
                                      (float)acc[mi][3][r] * sbv[3]));
                v = fmaxf(v, __shfl_xor(v, 1));
                v = fmaxf(v, __shfl_xor(v, 2));
                v = fmaxf(v, __shfl_xor(v, 4));
                v = fmaxf(v, __shfl_xor(v, 8));
                if (mrow == 0) {
                    const int row = row0 + mi * 16 + r;
                    atomicMax(&out[row], enc_f(v * sa[row]));
                }
            }
        }
    }
    #undef STAGE_A
    #undef STAGE_B
    #undef GLOAD
}

__global__ void decode_out_k(unsigned* __restrict__ u) {
    int i = blockIdx.x * 256 + threadIdx.x;
    ((float*)u)[i] = dec_f(u[i]);
}

extern "C" void kernel_launch(void* const* d_in, const int* in_sizes, int n_in,
                              void* d_out, int out_size, void* d_ws, size_t ws_size,
                              hipStream_t stream) {
    (void)in_sizes; (void)n_in; (void)out_size; (void)ws_size;
    const float* ex = (const float*)d_in[0];
    const float* ey = (const float*)d_in[1];
    // ws layout: qx[8192*768 B] ++ qy[8192*768 B] ++ scales[16384 f32]  (~12.6 MB)
    signed char* q = (signed char*)d_ws;
    float* scales  = (float*)(q + 2 * (size_t)NROWS * KDIM);
    unsigned* outu = (unsigned*)d_out;

    normalize_quant_k<<<(2 * NROWS) / 4, 256, 0, stream>>>(ex, ey, q, scales, outu);
    // grid: 32 row-tiles x 8 bcg = 256 blocks = 1/CU (128 KB LDS), 512 thr
    gemm_rowmax_i8_k<<<(NROWS / BM) * (NROWS / BN / NBC), 512, 0, stream>>>(
        q, q + (size_t)NROWS * KDIM, scales, scales + NROWS, outu);
    decode_out_k<<<NROWS / 256, 256, 0, stream>>>(outu);
}

// Round 6
// 167.783 us; speedup vs baseline: 1.0931x; 1.0931x over previous
//
#include <hip/hip_runtime.h>
#include <math.h>

#define NROWS 8192
#define KDIM  768            // bytes per i8 row
#define BM 128
#define BN 128
#define HB 64                // k-step bytes per row = one 16x16x64 MFMA
#define KT2 (KDIM / HB)      // 12 k-steps per bc sweep
#define NBC 4                // bc tiles swept per block
#define NT_ALL (NBC * KT2)   // 48 staged k-steps per block
#define NBCG (NROWS / BN / NBC)  // 16 -> grid 64*16 = 1024 = 4/CU

typedef int i32x4 __attribute__((ext_vector_type(4)));  // i8 MFMA A/B frag (16 B) and C/D

// monotonic float<->uint encoding so atomicMax(uint) == float max
static __device__ __forceinline__ unsigned enc_f(float f) {
    unsigned x = __float_as_uint(f);
    return (x & 0x80000000u) ? ~x : (x | 0x80000000u);
}
static __device__ __forceinline__ float dec_f(unsigned u) {
    unsigned x = (u & 0x80000000u) ? (u ^ 0x80000000u) : ~u;
    return __uint_as_float(x);
}

// one wave per row: fp32 normalize (exact), then symmetric int8 quantization
// with per-row scale amax/127. blocks 0..31 also init the out buffer.
__global__ __launch_bounds__(256) void normalize_quant_k(
        const float* __restrict__ ex, const float* __restrict__ ey,
        signed char* __restrict__ q, float* __restrict__ scales,
        unsigned* __restrict__ out) {
    if (blockIdx.x < NROWS / 256)
        out[blockIdx.x * 256 + threadIdx.x] = enc_f(-INFINITY);
    const int wave = threadIdx.x >> 6, lane = threadIdx.x & 63;
    const int grow = blockIdx.x * 4 + wave;          // 0..16383
    const float* src = (grow < NROWS) ? ex : ey;
    const int row = grow & (NROWS - 1);
    const float4* xr = (const float4*)(src + (size_t)row * KDIM);  // 192 float4
    float4 v[3];
    #pragma unroll
    for (int g = 0; g < 3; ++g) v[g] = xr[lane + g * 64];
    float ss = 0.f, am = 0.f;
    #pragma unroll
    for (int g = 0; g < 3; ++g) {
        ss += v[g].x * v[g].x + v[g].y * v[g].y + v[g].z * v[g].z + v[g].w * v[g].w;
        am = fmaxf(am, fmaxf(fmaxf(fabsf(v[g].x), fabsf(v[g].y)),
                             fmaxf(fabsf(v[g].z), fabsf(v[g].w))));
    }
    #pragma unroll
    for (int off = 32; off > 0; off >>= 1) {
        ss += __shfl_xor(ss, off);
        am = fmaxf(am, __shfl_xor(am, off));
    }
    const float scale = 1.0f / fmaxf(sqrtf(ss), 1e-8f);
    am = fmaxf(am * scale, 1e-12f);        // amax of the NORMALIZED row
    if (lane == 0) scales[grow] = am * (1.0f / 127.0f);
    const float si = scale * (127.0f / am);            // raw -> int8 code
    int* dr = (int*)(q + (size_t)grow * KDIM);         // 192 packed ints / row
    #pragma unroll
    for (int g = 0; g < 3; ++g) {
        int qx = min(127, max(-127, __float2int_rn(v[g].x * si)));
        int qy = min(127, max(-127, __float2int_rn(v[g].y * si)));
        int qz = min(127, max(-127, __float2int_rn(v[g].z * si)));
        int qw = min(127, max(-127, __float2int_rn(v[g].w * si)));
        dr[lane + g * 64] = (qx & 0xff) | ((qy & 0xff) << 8) |
                            ((qz & 0xff) << 16) | ((qw & 0xff) << 24);
    }
}

// R4 structure (128^2, 4 waves, 4 blocks/CU, 2D XCD decode — best: 79.4 us,
// 27% MfmaUtil) upgraded with the T3 "minimum 2-phase" pipeline:
// double-buffered BKB=64 tiles (LDS 2x16 KB, still 32 KB -> 4 blocks/CU kept),
// per k-step: STAGE(t+1)->buf^1, ds_read+MFMA on buf, vmcnt(0)+s_barrier.
// Loads for t+1 overlap the ~500cy compute of t (was: full drain between
// stage and compute every tile). Hazards: WAR — reads of buf^1 retired via
// compiler lgkmcnt before prior barrier; RAW — each wave's own vmcnt(0)
// precedes its barrier; asm memory clobber fences compiler reordering.
// LDS swizzle (R5-verified on HW, 0 conflicts): row pairs in 128-B stripes,
//   L(row,ch) = (row>>1)*128 + ((((row&1)<<2)|ch) ^ ((row>>1)&7))*16
// staged via linear gload_lds dest + inverse-swizzled per-lane global source.
__global__ __launch_bounds__(256, 4) void gemm_rowmax_i8_k(
        const signed char* __restrict__ A, const signed char* __restrict__ B,
        const float* __restrict__ sa, const float* __restrict__ sb,
        unsigned* __restrict__ out) {
    __shared__ __attribute__((aligned(128))) signed char As[2][BM * HB];  // 16 KB
    __shared__ __attribute__((aligned(128))) signed char Bs[2][BN * HB];  // 16 KB

    const int tid  = threadIdx.x;
    const int wave = tid >> 6, lane = tid & 63;
    // 2D XCD-aware decode (R4-proven: FETCH 102->18.6 MB). Bijective.
    const int xcd = blockIdx.x & 7;        // dispatch round-robins XCDs
    const int idx = blockIdx.x >> 3;       // 0..127 within XCD
    const int br  = (xcd >> 1) * 16 + (idx & 15);   // 0..63
    const int bcg = (xcd & 1) * 8 + (idx >> 4);     // 0..15

    // --- staging: per k-step, wave w loads rows w*32..w*32+31 of A and B
    // (2 gloads each). Per-lane inverse-swizzle source mapping:
    //   u = (lane&7) ^ (lane>>3);  srow = (lane>>3)*2 + (u>>2);  chunk = u&3
    const int u_     = (lane & 7) ^ (lane >> 3);
    const int srow   = ((lane >> 3) << 1) + (u_ >> 2);   // 0..15
    const int gch    = (u_ & 3) * 16;                    // byte chunk in 64-B slice
    const signed char* aStage =
        A + (size_t)(br * BM + wave * 32 + srow) * KDIM + gch;
    const int ldsW = wave * 2048;                        // 16 stripes x 128 B

    // --- compute geometry: wave (wm,wn) owns 64x64; frags 4mi x 4ni of 16x16
    const int wm = (wave >> 1) * 64, wn = (wave & 1) * 64;
    const int quad = lane >> 4, mrow = lane & 15;
    const int slot = (((mrow & 1) << 2) | quad) ^ ((mrow >> 1) & 7);
    const int aOff = ((wm >> 1) + (mrow >> 1)) * 128 + slot * 16;  // + mi*1024
    const int bOff = ((wn >> 1) + (mrow >> 1)) * 128 + slot * 16;  // + ni*1024
    const int row0 = br * BM + wm + quad * 4;

    #define GLOAD(gp, lp)                                                         \
        __builtin_amdgcn_global_load_lds(                                         \
            (const __attribute__((address_space(1))) void*)(gp),                  \
            (__attribute__((address_space(3))) void*)(lp), 16, 0, 0)

    // stage k-step s (bi = s/KT2, kt = s%KT2) into buffer (s&1)
    #define STAGE(sidx) do {                                                      \
        const int s_ = (sidx);                                                    \
        const int bi_ = s_ / KT2, kt_ = s_ % KT2;                                 \
        const signed char* ag_ = aStage + kt_ * HB;                               \
        const signed char* bg_ = B + (size_t)((bcg * NBC + bi_) * BN              \
                                 + wave * 32 + srow) * KDIM + gch + kt_ * HB;     \
        signed char* la_ = &As[s_ & 1][ldsW];                                     \
        signed char* lb_ = &Bs[s_ & 1][ldsW];                                     \
        GLOAD(ag_, la_);  GLOAD(ag_ + 16 * KDIM, la_ + 1024);                     \
        GLOAD(bg_, lb_);  GLOAD(bg_ + 16 * KDIM, lb_ + 1024);                     \
    } while (0)

    // prologue: stage k-step 0, drain, rendezvous
    STAGE(0);
    asm volatile("s_waitcnt vmcnt(0)" ::: "memory");
    __builtin_amdgcn_s_barrier();

    int t = 0;
    #pragma unroll 1
    for (int bi = 0; bi < NBC; ++bi) {
        i32x4 acc[4][4] = {};
        #pragma unroll 1
        for (int kt = 0; kt < KT2; ++kt, ++t) {
            // issue next-tile loads FIRST: they overlap this tile's compute
            if (t + 1 < NT_ALL) STAGE(t + 1);

            const int cb = t & 1;
            const signed char* aP = &As[cb][aOff];
            const signed char* bP = &Bs[cb][bOff];
            i32x4 af[4], bfr[4];
            #pragma unroll
            for (int mi = 0; mi < 4; ++mi)
                af[mi] = *(const i32x4*)(aP + mi * 1024);
            #pragma unroll
            for (int ni = 0; ni < 4; ++ni)
                bfr[ni] = *(const i32x4*)(bP + ni * 1024);

            __builtin_amdgcn_s_setprio(1);
            #pragma unroll
            for (int mi = 0; mi < 4; ++mi)
                #pragma unroll
                for (int ni = 0; ni < 4; ++ni)
                    acc[mi][ni] = __builtin_amdgcn_mfma_i32_16x16x64_i8(
                        af[mi], bfr[ni], acc[mi][ni], 0, 0, 0);
            __builtin_amdgcn_s_setprio(0);

            // one drain+barrier per k-step: next tile ready for everyone
            asm volatile("s_waitcnt vmcnt(0)" ::: "memory");
            __builtin_amdgcn_s_barrier();
        }

        // epilogue: registers + global only (no LDS -> no extra barrier).
        // C/D layout: col = mrow, row = quad*4 + reg (dtype-independent).
        const int bc = bcg * NBC + bi;
        float sbv[4];
        #pragma unroll
        for (int ni = 0; ni < 4; ++ni)
            sbv[ni] = sb[bc * BN + wn + ni * 16 + mrow];
        #pragma unroll
        for (int mi = 0; mi < 4; ++mi) {
            #pragma unroll
            for (int r = 0; r < 4; ++r) {
                float v = fmaxf(fmaxf((float)acc[mi][0][r] * sbv[0],
                                      (float)acc[mi][1][r] * sbv[1]),
                                fmaxf((float)acc[mi][2][r] * sbv[2],
                                      (float)acc[mi][3][r] * sbv[3]));
                v = fmaxf(v, __shfl_xor(v, 1));
                v = fmaxf(v, __shfl_xor(v, 2));
                v = fmaxf(v, __shfl_xor(v, 4));
                v = fmaxf(v, __shfl_xor(v, 8));
                if (mrow == 0) {
                    const int row = row0 + mi * 16 + r;
                    atomicMax(&out[row], enc_f(v * sa[row]));
                }
            }
        }
    }
    #undef STAGE
    #undef GLOAD
}

__global__ void decode_out_k(unsigned* __restrict__ u) {
    int i = blockIdx.x * 256 + threadIdx.x;
    ((float*)u)[i] = dec_f(u[i]);
}

extern "C" void kernel_launch(void* const* d_in, const int* in_sizes, int n_in,
                              void* d_out, int out_size, void* d_ws, size_t ws_size,
                              hipStream_t stream) {
    (void)in_sizes; (void)n_in; (void)out_size; (void)ws_size;
    const float* ex = (const float*)d_in[0];
    const float* ey = (const float*)d_in[1];
    // ws layout: qx[8192*768 B] ++ qy[8192*768 B] ++ scales[16384 f32]  (~12.6 MB)
    signed char* q = (signed char*)d_ws;
    float* scales  = (float*)(q + 2 * (size_t)NROWS * KDIM);
    unsigned* outu = (unsigned*)d_out;

    normalize_quant_k<<<(2 * NROWS) / 4, 256, 0, stream>>>(ex, ey, q, scales, outu);
    gemm_rowmax_i8_k<<<(NROWS / BM) * NBCG, 256, 0, stream>>>(
        q, q + (size_t)NROWS * KDIM, scales, scales + NROWS, outu);
    decode_out_k<<<NROWS / 256, 256, 0, stream>>>(outu);
}

// Round 7
// 156.258 us; speedup vs baseline: 1.1737x; 1.0738x over previous
//
#include <hip/hip_runtime.h>
#include <math.h>

#define NROWS 8192
#define KDIM  768            // elements per row; for i8 buffers this is also BYTES
#define BM 256
#define BN 128
#define BKB 128              // K-tile bytes per row (128 i8 = 2 MFMA k-steps of 64)
#define KTILES (KDIM / BKB)  // 6
#define NBC 4                // bc tiles swept per block
#define NBCG (NROWS / BN / NBC)  // 16
#define NBR  (NROWS / BM)        // 32 -> grid 512 = 2/CU at 48 KB LDS

typedef int i32x4 __attribute__((ext_vector_type(4)));  // i8 MFMA A/B frag (16 B) and C/D

// monotonic float<->uint encoding so atomicMax(uint) == float max
static __device__ __forceinline__ unsigned enc_f(float f) {
    unsigned x = __float_as_uint(f);
    return (x & 0x80000000u) ? ~x : (x | 0x80000000u);
}
static __device__ __forceinline__ float dec_f(unsigned u) {
    unsigned x = (u & 0x80000000u) ? (u ^ 0x80000000u) : ~u;
    return __uint_as_float(x);
}

// one wave per row: fp32 normalize (exact), then symmetric int8 quantization
// with per-row scale amax/127. blocks 0..31 also init the out buffer.
__global__ __launch_bounds__(256) void normalize_quant_k(
        const float* __restrict__ ex, const float* __restrict__ ey,
        signed char* __restrict__ q, float* __restrict__ scales,
        unsigned* __restrict__ out) {
    if (blockIdx.x < NROWS / 256)
        out[blockIdx.x * 256 + threadIdx.x] = enc_f(-INFINITY);
    const int wave = threadIdx.x >> 6, lane = threadIdx.x & 63;
    const int grow = blockIdx.x * 4 + wave;          // 0..16383
    const float* src = (grow < NROWS) ? ex : ey;
    const int row = grow & (NROWS - 1);
    const float4* xr = (const float4*)(src + (size_t)row * KDIM);  // 192 float4
    float4 v[3];
    #pragma unroll
    for (int g = 0; g < 3; ++g) v[g] = xr[lane + g * 64];
    float ss = 0.f, am = 0.f;
    #pragma unroll
    for (int g = 0; g < 3; ++g) {
        ss += v[g].x * v[g].x + v[g].y * v[g].y + v[g].z * v[g].z + v[g].w * v[g].w;
        am = fmaxf(am, fmaxf(fmaxf(fabsf(v[g].x), fabsf(v[g].y)),
                             fmaxf(fabsf(v[g].z), fabsf(v[g].w))));
    }
    #pragma unroll
    for (int off = 32; off > 0; off >>= 1) {
        ss += __shfl_xor(ss, off);
        am = fmaxf(am, __shfl_xor(am, off));
    }
    const float scale = 1.0f / fmaxf(sqrtf(ss), 1e-8f);
    am = fmaxf(am * scale, 1e-12f);        // amax of the NORMALIZED row
    if (lane == 0) scales[grow] = am * (1.0f / 127.0f);
    const float si = scale * (127.0f / am);            // raw -> int8 code
    int* dr = (int*)(q + (size_t)grow * KDIM);         // 192 packed ints / row
    #pragma unroll
    for (int g = 0; g < 3; ++g) {
        int qx = min(127, max(-127, __float2int_rn(v[g].x * si)));
        int qy = min(127, max(-127, __float2int_rn(v[g].y * si)));
        int qz = min(127, max(-127, __float2int_rn(v[g].z * si)));
        int qw = min(127, max(-127, __float2int_rn(v[g].w * si)));
        dr[lane + g * 64] = (qx & 0xff) | ((qy & 0xff) << 8) |
                            ((qz & 0xff) << 16) | ((qw & 0xff) << 24);
    }
}

// R4 structure scaled to BM=256 x BN=128 (8 waves, 512 thr, 2 blocks/CU):
// staging traffic is tile-determined (bytes = MACs/(BM*BN/(BM+BN))); 128^2
// gave 805 MB L2->LDS, this gives 604 MB (-25%) — the dominant serial term
// in the 2-sync loop. Per-wave everything is IDENTICAL to the proven R4
// kernel: 64x64 wave tile, 4x4 frags of 16x16x64 i8, chunk-XOR swizzle
// (slot s of row r holds chunk s^(r&7); 0 conflicts on HW), 2 syncthreads
// per K-tile. Per wave per K-tile: 4 A-issues + 2 B-issues of 1 KB.
// XCD decode: 8br x 8bcg rectangle per XCD -> working set A 8x196KB +
// B 32x98KB = 4.7 MB ~= L2. Bijective.
__global__ __launch_bounds__(512, 4) void gemm_rowmax_i8_k(
        const signed char* __restrict__ A, const signed char* __restrict__ B,
        const float* __restrict__ sa, const float* __restrict__ sb,
        unsigned* __restrict__ out) {
    __shared__ signed char As[BM * BKB];   // 32 KB
    __shared__ signed char Bs[BN * BKB];   // 16 KB

    const int tid  = threadIdx.x;
    const int wave = tid >> 6, lane = tid & 63;   // wave 0..7
    // 2D XCD-aware decode (R4-proven family; speed-only heuristic)
    const int xcd = blockIdx.x & 7;        // dispatch round-robins XCDs
    const int idx = blockIdx.x >> 3;       // 0..63 within XCD
    const int br  = (xcd >> 1) * 8 + (idx & 7);   // 0..31
    const int bcg = (xcd & 1) * 8 + (idx >> 3);   // 0..15

    // staging: wave issue = 8 rows x 128 B; slot s of row r holds chunk s^(r&7).
    // rows step by 8 per issue-slot so row&7 == lane>>3 always (swizzle source
    // chunk is issue-invariant, same as R4).
    const int srow   = lane >> 3;
    const int gchunk = (lane & 7) ^ srow;
    const int scol   = gchunk * 16;        // bytes
    // A issue i (0..3) covers rows (wave + 8i)*8 + srow -> +i*64 rows
    const signed char* aStage = A + (size_t)(br * BM + wave * 8 + srow) * KDIM + scol;
    signed char* lA = As + wave * 1024;    // + i*8192
    signed char* lB = Bs + wave * 1024;    // + j*8192

    // compute geometry: 8 waves = 4M x 2N; wave tile 64x64, 4x4 of 16x16x64
    const int wm = (wave >> 1) * 64, wn = (wave & 1) * 64;
    const int quad = lane >> 4, mrow = lane & 15;
    const int c0 = quad ^ (mrow & 7);      // swizzled chunk slot; ks=1: ^4
    const signed char* aBase = As + (wm + mrow) * BKB;
    const signed char* bBase = Bs + (wn + mrow) * BKB;
    const int row0 = br * BM + wm + quad * 4;

    #pragma unroll 1
    for (int bi = 0; bi < NBC; ++bi) {
        const int bc = bcg * NBC + bi;
        // B issue j (0..1) covers rows (wave + 8j)*8 + srow -> +j*64 rows
        const signed char* bStage =
            B + (size_t)(bc * BN + wave * 8 + srow) * KDIM + scol;

        i32x4 acc[4][4] = {};

        #pragma unroll 1
        for (int kt = 0; kt < KTILES; ++kt) {
            __syncthreads();   // previous tile's LDS reads done
            #pragma unroll
            for (int i = 0; i < 4; ++i)
                __builtin_amdgcn_global_load_lds(
                    (const __attribute__((address_space(1))) void*)(aStage + kt * BKB + i * 49152),
                    (__attribute__((address_space(3))) void*)(lA + i * 8192), 16, 0, 0);
            #pragma unroll
            for (int j = 0; j < 2; ++j)
                __builtin_amdgcn_global_load_lds(
                    (const __attribute__((address_space(1))) void*)(bStage + kt * BKB + j * 49152),
                    (__attribute__((address_space(3))) void*)(lB + j * 8192), 16, 0, 0);
            __syncthreads();   // staging complete

            #pragma unroll 1
            for (int ks = 0; ks < 2; ++ks) {
                const int ck = c0 ^ (ks << 2);
                i32x4 af[4], bfr[4];
                #pragma unroll
                for (int mi = 0; mi < 4; ++mi)
                    af[mi] = *(const i32x4*)(aBase + mi * 16 * BKB + ck * 16);
                #pragma unroll
                for (int ni = 0; ni < 4; ++ni)
                    bfr[ni] = *(const i32x4*)(bBase + ni * 16 * BKB + ck * 16);
                #pragma unroll
                for (int mi = 0; mi < 4; ++mi)
                    #pragma unroll
                    for (int ni = 0; ni < 4; ++ni)
                        acc[mi][ni] = __builtin_amdgcn_mfma_i32_16x16x64_i8(
                            af[mi], bfr[ni], acc[mi][ni], 0, 0, 0);
            }
        }

        // epilogue: fold sb[col] per ni, in-lane ni max, shfl-max over 16 cols,
        // then *sa[row]. C/D layout: col = lane&15, row = quad*4 + reg.
        float sbv[4];
        #pragma unroll
        for (int ni = 0; ni < 4; ++ni)
            sbv[ni] = sb[bc * BN + wn + ni * 16 + mrow];
        #pragma unroll
        for (int mi = 0; mi < 4; ++mi) {
            #pragma unroll
            for (int r = 0; r < 4; ++r) {
                float v = fmaxf(fmaxf((float)acc[mi][0][r] * sbv[0],
                                      (float)acc[mi][1][r] * sbv[1]),
                                fmaxf((float)acc[mi][2][r] * sbv[2],
                                      (float)acc[mi][3][r] * sbv[3]));
                v = fmaxf(v, __shfl_xor(v, 1));
                v = fmaxf(v, __shfl_xor(v, 2));
                v = fmaxf(v, __shfl_xor(v, 4));
                v = fmaxf(v, __shfl_xor(v, 8));
                if (mrow == 0) {
                    const int row = row0 + mi * 16 + r;
                    atomicMax(&out[row], enc_f(v * sa[row]));
                }
            }
        }
    }
}

__global__ void decode_out_k(unsigned* __restrict__ u) {
    int i = blockIdx.x * 256 + threadIdx.x;
    ((float*)u)[i] = dec_f(u[i]);
}

extern "C" void kernel_launch(void* const* d_in, const int* in_sizes, int n_in,
                              void* d_out, int out_size, void* d_ws, size_t ws_size,
                              hipStream_t stream) {
    (void)in_sizes; (void)n_in; (void)out_size; (void)ws_size;
    const float* ex = (const float*)d_in[0];
    const float* ey = (const float*)d_in[1];
    // ws layout: qx[8192*768 B] ++ qy[8192*768 B] ++ scales[16384 f32]  (~12.6 MB)
    signed char* q = (signed char*)d_ws;
    float* scales  = (float*)(q + 2 * (size_t)NROWS * KDIM);
    unsigned* outu = (unsigned*)d_out;

    normalize_quant_k<<<(2 * NROWS) / 4, 256, 0, stream>>>(ex, ey, q, scales, outu);
    // grid: 32 br x 16 bcg = 512 blocks = 2/CU (48 KB LDS), 512 thr
    gemm_rowmax_i8_k<<<NBR * NBCG, 512, 0, stream>>>(
        q, q + (size_t)NROWS * KDIM, scales, scales + NROWS, outu);
    decode_out_k<<<NROWS / 256, 256, 0, stream>>>(outu);
}